// Round 1
// baseline (220.609 us; speedup 1.0000x reference)
//
#include <hip/hip_runtime.h>
#include <math.h>

// Problem constants: x (8, 64, 4, 128, 128) fp32; k=2, s=2, p=0 -> Ho=Wo=64, L=4096, K=4
#define NB 8
#define NG 64
#define NQ 4
#define NH 128
#define NW 128
#define HO 64
#define WOUT 64
#define NL 4096
#define EPSF 1e-8f

// mag layout in ws: [b][g][kk][l], fp32, 8*64*4*4096 = 32 MiB
// S layout: [b][g][kk] fp64, 2048 entries = 16 KiB
#define MAG_BYTES ((size_t)NB * NG * 4 * NL * sizeof(float))
#define S_COUNT (NB * NG * 4)

// Pass A: compute per-window quaternion magnitudes; optionally store them; always
// accumulate per-(b,g,kk) sums over L in fp64 via wave-reduce + atomicAdd.
// One thread per (b,g,ho,wo): t = ((b*64+g)*64+ho)*64+wo. Wave = one ho row (64 wo).
template <bool STORE_MAG>
__global__ __launch_bounds__(256) void mag_kernel(const float* __restrict__ x,
                                                  float* __restrict__ mag,
                                                  double* __restrict__ S) {
    int t = blockIdx.x * 256 + threadIdx.x;
    int wo = t & 63;
    int ho = (t >> 6) & 63;
    int g  = (t >> 12) & 63;
    int b  = t >> 18;

    const float2* xp = (const float2*)x;
    // float2 index of (b,g,q=0) plane start
    long base2 = (long)(b * NG + g) * NQ * (NH * NW / 2);

    float sq[4] = {0.f, 0.f, 0.f, 0.f};
#pragma unroll
    for (int q = 0; q < NQ; q++) {
#pragma unroll
        for (int i = 0; i < 2; i++) {
            float2 v = xp[base2 + (long)q * (NH * NW / 2) + (2 * ho + i) * (NW / 2) + wo];
            int k0 = i * 2;
            // exact np order: sum over q of u*u, sequential, no FMA contraction
            sq[k0]     = __fadd_rn(sq[k0],     __fmul_rn(v.x, v.x));
            sq[k0 + 1] = __fadd_rn(sq[k0 + 1], __fmul_rn(v.y, v.y));
        }
    }

    int l = ho * 64 + wo;
    long mbase = (long)(b * NG + g) * 4 * NL + l;
    int lane = threadIdx.x & 63;
    int sidx = (b * NG + g) * 4;
#pragma unroll
    for (int k = 0; k < 4; k++) {
        float m = __fsqrt_rn(sq[k]);
        if (STORE_MAG) mag[mbase + k * NL] = m;
        double d = (double)m;
#pragma unroll
        for (int off = 32; off; off >>= 1) d += __shfl_xor(d, off, 64);
        if (lane == k * 16) atomicAdd(&S[sidx + k], d);
    }
}

// Pass B: one thread per (b,l). Loop over g: entropy in fp32, first-max argmax,
// then gather winning group's raw 2x2x4 block -> contiguous 16 floats of out.
template <bool USE_MAG>
__global__ __launch_bounds__(64) void pool_kernel(const float* __restrict__ x,
                                                  const float* __restrict__ mag,
                                                  const double* __restrict__ S,
                                                  float* __restrict__ out) {
    int b = blockIdx.y;
    int l = blockIdx.x * 64 + threadIdx.x;
    int ho = l >> 6;
    int wo = l & 63;

    __shared__ float rcpS[NG * 4];
    for (int i = threadIdx.x; i < NG * 4; i += 64) {
        float denom = __fadd_rn((float)S[b * NG * 4 + i], EPSF);
        rcpS[i] = (float)(1.0 / (double)denom);
    }
    __syncthreads();

    const float* magb = mag + (long)b * NG * 4 * NL + l;
    const float2* xp = (const float2*)x;

    float best = -INFINITY;
    int bestg = 0;
    for (int g = 0; g < NG; g++) {
        float mk[4];
        if (USE_MAG) {
            const float* mg = magb + g * 4 * NL;
#pragma unroll
            for (int k = 0; k < 4; k++) mk[k] = mg[k * NL];
        } else {
            long base2 = (long)(b * NG + g) * NQ * (NH * NW / 2);
            float sq[4] = {0.f, 0.f, 0.f, 0.f};
#pragma unroll
            for (int q = 0; q < NQ; q++) {
#pragma unroll
                for (int i = 0; i < 2; i++) {
                    float2 v = xp[base2 + (long)q * (NH * NW / 2) + (2 * ho + i) * (NW / 2) + wo];
                    sq[i * 2]     = __fadd_rn(sq[i * 2],     __fmul_rn(v.x, v.x));
                    sq[i * 2 + 1] = __fadd_rn(sq[i * 2 + 1], __fmul_rn(v.y, v.y));
                }
            }
#pragma unroll
            for (int k = 0; k < 4; k++) mk[k] = __fsqrt_rn(sq[k]);
        }
        float e = 0.f;
#pragma unroll
        for (int k = 0; k < 4; k++) {
            float p = __fmul_rn(mk[k], rcpS[g * 4 + k]);
            float lg = logf(__fadd_rn(p, EPSF));
            e = __fadd_rn(e, __fmul_rn(p, lg));
        }
        e = -e;
        if (e > best) { best = e; bestg = g; }  // strict > keeps FIRST max (matches argmax)
    }

    // gather: u[b, bestg, q, kk, l] = x[b, bestg, q, 2ho+i, 2wo+j], kk = i*2+j
    long base2 = (long)(b * NG + bestg) * NQ * (NH * NW / 2);
    float4* o = (float4*)out + ((long)b * (NL * 16) + (long)l * 16) / 4;
#pragma unroll
    for (int q = 0; q < NQ; q++) {
        float2 t0 = xp[base2 + (long)q * (NH * NW / 2) + (2 * ho) * (NW / 2) + wo];
        float2 t1 = xp[base2 + (long)q * (NH * NW / 2) + (2 * ho + 1) * (NW / 2) + wo];
        o[q] = make_float4(t0.x, t0.y, t1.x, t1.y);
    }
}

extern "C" void kernel_launch(void* const* d_in, const int* in_sizes, int n_in,
                              void* d_out, int out_size, void* d_ws, size_t ws_size,
                              hipStream_t stream) {
    const float* x = (const float*)d_in[0];
    float* out = (float*)d_out;

    bool have_mag_ws = ws_size >= MAG_BYTES + S_COUNT * sizeof(double);

    float* mag;
    double* S;
    if (have_mag_ws) {
        mag = (float*)d_ws;
        S = (double*)((char*)d_ws + MAG_BYTES);
    } else {
        mag = nullptr;
        S = (double*)d_ws;  // only 16 KiB needed
    }

    hipMemsetAsync(S, 0, S_COUNT * sizeof(double), stream);

    int total = NB * NG * HO * WOUT;       // 2,097,152 threads
    int blocksA = total / 256;             // 8192
    if (have_mag_ws) {
        mag_kernel<true><<<blocksA, 256, 0, stream>>>(x, mag, S);
        pool_kernel<true><<<dim3(NL / 64, NB), 64, 0, stream>>>(x, mag, S, out);
    } else {
        mag_kernel<false><<<blocksA, 256, 0, stream>>>(x, mag, S);
        pool_kernel<false><<<dim3(NL / 64, NB), 64, 0, stream>>>(x, mag, S, out);
    }
}

// Round 2
// 212.964 us; speedup vs baseline: 1.0359x; 1.0359x over previous
//
#include <hip/hip_runtime.h>
#include <math.h>

// x: (8, 64, 4, 128, 128) fp32; k=2, s=2, p=0 -> Ho=Wo=64, L=4096, K=4
#define NB 8
#define NG 64
#define NQ 4
#define NH 128
#define NW 128
#define NL 4096
#define EPSF 1e-8f

// ws layout: winner[NB*NL] u64 | S[NB*NG*4] f64 | mag[NB*NG*4*NL] f32
#define WINNER_CT (NB * NL)                 // 32768
#define S_CT (NB * NG * 4)                  // 2048
#define MAG_OFF ((size_t)(WINNER_CT + S_CT) * 8)

// Pass A: per-window quaternion magnitudes. One thread per (b,g,ho,wp), wp covers
// 2 adjacent windows via one float4 row-load per (q,row). Stores mag as float2,
// wave-reduces fp64 k-sums (wave = 2 full ho rows), 4 atomics/wave.
__global__ __launch_bounds__(256) void mag_kernel(const float4* __restrict__ x4,
                                                  float2* __restrict__ mag2,
                                                  double* __restrict__ S) {
    int t = blockIdx.x * 256 + threadIdx.x;
    int wp = t & 31;
    int ho = (t >> 5) & 63;
    int g  = (t >> 11) & 63;
    int b  = t >> 17;

    long base4 = (long)((b * NG + g) * NQ) * (NH * NW / 4);
    float sqA[4] = {0.f, 0.f, 0.f, 0.f};
    float sqB[4] = {0.f, 0.f, 0.f, 0.f};
#pragma unroll
    for (int q = 0; q < NQ; q++) {
#pragma unroll
        for (int i = 0; i < 2; i++) {
            float4 v = x4[base4 + (long)q * (NH * NW / 4) + (2 * ho + i) * (NW / 4) + wp];
            // exact np order: sequential over q, no FMA contraction
            sqA[i * 2]     = __fadd_rn(sqA[i * 2],     __fmul_rn(v.x, v.x));
            sqA[i * 2 + 1] = __fadd_rn(sqA[i * 2 + 1], __fmul_rn(v.y, v.y));
            sqB[i * 2]     = __fadd_rn(sqB[i * 2],     __fmul_rn(v.z, v.z));
            sqB[i * 2 + 1] = __fadd_rn(sqB[i * 2 + 1], __fmul_rn(v.w, v.w));
        }
    }

    int lane = threadIdx.x & 63;
    int sidx = (b * NG + g) * 4;
    // mag element ((b*64+g)*4+k)*4096 + ho*64 + 2*wp  -> float2 index /2
    long m2base = (long)sidx * (NL / 2) + ho * 32 + wp;
#pragma unroll
    for (int k = 0; k < 4; k++) {
        float mA = __fsqrt_rn(sqA[k]);
        float mB = __fsqrt_rn(sqB[k]);
        mag2[m2base + (long)k * (NL / 2)] = make_float2(mA, mB);
        double d = (double)mA + (double)mB;
#pragma unroll
        for (int off = 32; off; off >>= 1) d += __shfl_xor(d, off, 64);
        if (lane == k * 16) atomicAdd(&S[sidx + k], d);
    }
}

// Pass B: one thread per (b,g,l). Entropy in fp32 (same op order as R1 bitwise-
// passing kernel), pack (monotonic ent bits, 63-g) and atomicMax per (b,l).
__global__ __launch_bounds__(256) void ent_kernel(const float* __restrict__ mag,
                                                  const double* __restrict__ S,
                                                  unsigned long long* __restrict__ winner) {
    int t = blockIdx.x * 256 + threadIdx.x;
    int l = t & 4095;
    int g = (t >> 12) & 63;
    int b = t >> 18;
    int sidx = (b * NG + g) * 4;   // block-uniform: one 256-block spans a single (b,g)

    __shared__ float rcp4[4];
    if (threadIdx.x < 4) {
        float denom = __fadd_rn((float)S[sidx + threadIdx.x], EPSF);
        rcp4[threadIdx.x] = (float)(1.0 / (double)denom);
    }
    __syncthreads();

    long mbase = (long)sidx * NL + l;
    float e = 0.f;
#pragma unroll
    for (int k = 0; k < 4; k++) {
        float p = __fmul_rn(mag[mbase + (long)k * NL], rcp4[k]);
        float lg = logf(__fadd_rn(p, EPSF));
        e = __fadd_rn(e, __fmul_rn(p, lg));
    }
    float f = -e;   // ent
    unsigned int bits = __float_as_uint(f);
    unsigned int key = (bits & 0x80000000u) ? ~bits : (bits | 0x80000000u);
    unsigned long long pk = ((unsigned long long)key << 32) | (unsigned long long)(63 - g);
    atomicMax(&winner[b * NL + l], pk);
}

// Pass C: one thread per (b,l,q). Winner broadcast within 4-lane groups, gather
// the 2x2 block, perfectly coalesced float4 store.
__global__ __launch_bounds__(256) void gather_kernel(const float2* __restrict__ x2,
                                                     const unsigned long long* __restrict__ winner,
                                                     float4* __restrict__ out4) {
    int t = blockIdx.x * 256 + threadIdx.x;   // t = (b*4096 + l)*4 + q
    int q = t & 3;
    int l = (t >> 2) & 4095;
    int b = t >> 14;
    unsigned long long w = winner[b * NL + l];
    int g = 63 - (int)(w & 63ull);
    int ho = l >> 6, wo = l & 63;
    long base2 = (long)((b * NG + g) * NQ + q) * (NH * NW / 2);
    float2 t0 = x2[base2 + (2 * ho) * (NW / 2) + wo];
    float2 t1 = x2[base2 + (2 * ho + 1) * (NW / 2) + wo];
    out4[t] = make_float4(t0.x, t0.y, t1.x, t1.y);
}

extern "C" void kernel_launch(void* const* d_in, const int* in_sizes, int n_in,
                              void* d_out, int out_size, void* d_ws, size_t ws_size,
                              hipStream_t stream) {
    const float* x = (const float*)d_in[0];
    float* out = (float*)d_out;

    unsigned long long* winner = (unsigned long long*)d_ws;
    double* S = (double*)((char*)d_ws + (size_t)WINNER_CT * 8);
    float* mag = (float*)((char*)d_ws + MAG_OFF);

    // zero winner + S in one shot (contiguous, 272 KiB)
    hipMemsetAsync(d_ws, 0, MAG_OFF, stream);

    // Pass A: 8*64*64*32 = 1,048,576 threads
    mag_kernel<<<(NB * NG * 64 * 32) / 256, 256, 0, stream>>>(
        (const float4*)x, (float2*)mag, S);
    // Pass B: 8*64*4096 = 2,097,152 threads
    ent_kernel<<<(NB * NG * NL) / 256, 256, 0, stream>>>(mag, S, winner);
    // Pass C: 8*4096*4 = 131,072 threads
    gather_kernel<<<(NB * NL * NQ) / 256, 256, 0, stream>>>(
        (const float2*)x, winner, (float4*)out);
}

// Round 3
// 210.498 us; speedup vs baseline: 1.0480x; 1.0117x over previous
//
#include <hip/hip_runtime.h>
#include <math.h>

// x: (8, 64, 4, 128, 128) fp32; k=2, s=2, p=0 -> Ho=Wo=64, L=4096, K=4
#define NB 8
#define NG 64
#define NQ 4
#define NH 128
#define NW 128
#define NL 4096
#define EPSF 1e-8f

// ws layout: winner[NB*NL] u64 = 256 KiB
#define WINNER_CT (NB * NL)

// Fused pass: one block per (b,g), 1024 threads. Each thread owns 2 float4
// column-positions (= 4 windows): computes quaternion mags into registers,
// block-reduces the per-k fp64 sums over L, broadcasts 1/(S+eps), computes
// entropy per window, packs (monotonic ent bits | 63-g), atomicMax per (b,l).
__global__ __launch_bounds__(1024) void fused_kernel(const float4* __restrict__ x4,
                                                     unsigned long long* __restrict__ winner) {
    int bg = blockIdx.x;          // b*64 + g
    int b = bg >> 6;
    int g = bg & 63;
    int tid = threadIdx.x;

    long base4 = (long)(bg * NQ) * (NH * NW / 4);

    float mg[2][2][4];            // [pos][windowA/B][k]
    double dsum[4] = {0.0, 0.0, 0.0, 0.0};
#pragma unroll
    for (int pp = 0; pp < 2; pp++) {
        int pos = tid + pp * 1024;          // [0,2048): ho = pos>>5, wp = pos&31
        int ho = pos >> 5, wp = pos & 31;
        float sqA[4] = {0.f, 0.f, 0.f, 0.f};
        float sqB[4] = {0.f, 0.f, 0.f, 0.f};
#pragma unroll
        for (int q = 0; q < NQ; q++) {
#pragma unroll
            for (int i = 0; i < 2; i++) {
                float4 v = x4[base4 + (long)q * (NH * NW / 4) + (2 * ho + i) * (NW / 4) + wp];
                // exact np order: sequential over q, no FMA contraction
                sqA[i * 2]     = __fadd_rn(sqA[i * 2],     __fmul_rn(v.x, v.x));
                sqA[i * 2 + 1] = __fadd_rn(sqA[i * 2 + 1], __fmul_rn(v.y, v.y));
                sqB[i * 2]     = __fadd_rn(sqB[i * 2],     __fmul_rn(v.z, v.z));
                sqB[i * 2 + 1] = __fadd_rn(sqB[i * 2 + 1], __fmul_rn(v.w, v.w));
            }
        }
#pragma unroll
        for (int k = 0; k < 4; k++) {
            float mA = __fsqrt_rn(sqA[k]);
            float mB = __fsqrt_rn(sqB[k]);
            mg[pp][0][k] = mA;
            mg[pp][1][k] = mB;
            dsum[k] += (double)mA + (double)mB;
        }
    }

    // block reduction of dsum[4] (fp64, order-insensitive; R1/R2 proved bitwise-OK)
#pragma unroll
    for (int k = 0; k < 4; k++) {
#pragma unroll
        for (int off = 32; off; off >>= 1) dsum[k] += __shfl_xor(dsum[k], off, 64);
    }
    __shared__ double lds[16][4];
    __shared__ float rcp4s[4];
    int wave = tid >> 6, lane = tid & 63;
    if (lane == 0) {
#pragma unroll
        for (int k = 0; k < 4; k++) lds[wave][k] = dsum[k];
    }
    __syncthreads();
    if (tid < 4) {
        double s = 0.0;
        for (int w = 0; w < 16; w++) s += lds[w][tid];
        float denom = __fadd_rn((float)s, EPSF);
        rcp4s[tid] = (float)(1.0 / (double)denom);
    }
    __syncthreads();
    float r0 = rcp4s[0], r1 = rcp4s[1], r2 = rcp4s[2], r3 = rcp4s[3];

    unsigned long long gk = (unsigned long long)(63 - g);
    unsigned long long* wrow = winner + b * NL;
#pragma unroll
    for (int pp = 0; pp < 2; pp++) {
        int pos = tid + pp * 1024;
        int ho = pos >> 5, wp = pos & 31;
#pragma unroll
        for (int w = 0; w < 2; w++) {
            float p0 = __fmul_rn(mg[pp][w][0], r0);
            float p1 = __fmul_rn(mg[pp][w][1], r1);
            float p2 = __fmul_rn(mg[pp][w][2], r2);
            float p3 = __fmul_rn(mg[pp][w][3], r3);
            float e = 0.f;
            e = __fadd_rn(e, __fmul_rn(p0, logf(__fadd_rn(p0, EPSF))));
            e = __fadd_rn(e, __fmul_rn(p1, logf(__fadd_rn(p1, EPSF))));
            e = __fadd_rn(e, __fmul_rn(p2, logf(__fadd_rn(p2, EPSF))));
            e = __fadd_rn(e, __fmul_rn(p3, logf(__fadd_rn(p3, EPSF))));
            float f = -e;
            unsigned int bits = __float_as_uint(f);
            unsigned int key = (bits & 0x80000000u) ? ~bits : (bits | 0x80000000u);
            int l = ho * 64 + 2 * wp + w;
            atomicMax(&wrow[l], ((unsigned long long)key << 32) | gk);
        }
    }
}

// Gather: one thread per (b,l,q); winner broadcast within 4-lane groups,
// perfectly coalesced float4 store to out.
__global__ __launch_bounds__(256) void gather_kernel(const float2* __restrict__ x2,
                                                     const unsigned long long* __restrict__ winner,
                                                     float4* __restrict__ out4) {
    int t = blockIdx.x * 256 + threadIdx.x;   // t = (b*4096 + l)*4 + q
    int q = t & 3;
    int l = (t >> 2) & 4095;
    int b = t >> 14;
    unsigned long long w = winner[b * NL + l];
    int g = 63 - (int)(w & 63ull);
    int ho = l >> 6, wo = l & 63;
    long base2 = (long)((b * NG + g) * NQ + q) * (NH * NW / 2);
    float2 t0 = x2[base2 + (2 * ho) * (NW / 2) + wo];
    float2 t1 = x2[base2 + (2 * ho + 1) * (NW / 2) + wo];
    out4[t] = make_float4(t0.x, t0.y, t1.x, t1.y);
}

extern "C" void kernel_launch(void* const* d_in, const int* in_sizes, int n_in,
                              void* d_out, int out_size, void* d_ws, size_t ws_size,
                              hipStream_t stream) {
    const float* x = (const float*)d_in[0];
    float* out = (float*)d_out;
    unsigned long long* winner = (unsigned long long*)d_ws;

    hipMemsetAsync(winner, 0, (size_t)WINNER_CT * 8, stream);

    // 512 blocks x 1024 threads: one block per (b,g)
    fused_kernel<<<NB * NG, 1024, 0, stream>>>((const float4*)x, winner);
    // 8*4096*4 = 131,072 threads
    gather_kernel<<<(NB * NL * NQ) / 256, 256, 0, stream>>>(
        (const float2*)x, winner, (float4*)out);
}